// Round 7
// baseline (163.509 us; speedup 1.0000x reference)
//
#include <hip/hip_runtime.h>
#include <math.h>

// ExpertRouter: B=8, N=4096, D=1024, E=2  -> rows = 32768
// Outputs (concatenated float32):
//   [0 .. 65535]        expert_weights  [rows,2]  (0/1)
//   [65536 .. 98303]    expert_decisions [rows]   (0/1, "both experts kept")
//   [98304]             gating_loss scalar
//
// R7 vs R6:
//  * single fused kernel: last-block-done finisher computes the scalar loss
//    (part[] store -> threadfence -> atomicAdd counter; finisher re-fences and
//    reduces 4096 triples). Counter zeroed per launch via hipMemsetAsync.
//  * parity-split butterfly: even lanes own row A, odd lanes own row B after a
//    1-stage pair exchange; 5 shared stages finish both rows. 18 shuffles/wave
//    (was 36) and no epilogue selects.

constexpr int D = 1024;
constexpr int ROWS = 32768;
constexpr int OUT_DEC = ROWS * 2;   // 65536
constexpr int OUT_LOSS = ROWS * 3;  // 98304
constexpr int BLOCKS = 4096;        // 16384 waves x 2 consecutive rows each
constexpr size_t PART_BYTES = (size_t)BLOCKS * 3 * sizeof(double);  // 96 KiB

static __device__ __forceinline__ float softplusf(float v) {
    // logaddexp(v, 0) = max(v,0) + log1p(exp(-|v|))  (matches jax.nn.softplus)
    return fmaxf(v, 0.0f) + log1pf(expf(-fabsf(v)));
}

__global__ __launch_bounds__(256) void router_fused(
    const float* __restrict__ x,        // [ROWS, D]
    const float* __restrict__ gate_w,   // [2, D]
    const float* __restrict__ noise_w,  // [2, D]
    const float* __restrict__ ns,       // [ROWS, 2]
    float* __restrict__ out,            // [ROWS*3 + 1]
    double* __restrict__ part,          // [BLOCKS*3]
    unsigned int* __restrict__ counter) // zeroed per launch
{
    const int t    = threadIdx.x;
    const int lane = t & 63;
    const int wid  = t >> 6;                      // wave in block (0..3)
    const int wave = blockIdx.x * 4 + wid;        // 0..16383
    const int r0   = wave * 2;                    // 2 consecutive rows per wave

    // ---- Stage folded weights in LDS: wd = g1-g0, wn0, wn1 (3 KiB). ----
    __shared__ float4 swd[256], swn0[256], swn1[256];
    {
        const float4* g4 = (const float4*)gate_w;
        const float4* n4 = (const float4*)noise_w;
        float4 g0 = g4[t], g1 = g4[256 + t];
        swd[t]  = make_float4(g1.x - g0.x, g1.y - g0.y, g1.z - g0.z, g1.w - g0.w);
        swn0[t] = n4[t];
        swn1[t] = n4[256 + t];
    }
    __syncthreads();

    // ---- Issue ALL x loads up-front: 2 rows x 4 float4 (unit-stride). ----
    const float4* xa4 = (const float4*)(x + (size_t)r0 * D);
    const float4* xb4 = xa4 + 256;
    float4 va[4], vb[4];
#pragma unroll
    for (int i = 0; i < 4; ++i) va[i] = xa4[64 * i + lane];
#pragma unroll
    for (int i = 0; i < 4; ++i) vb[i] = xb4[64 * i + lane];

    // Noise samples for rows r0, r0+1 (wave-uniform broadcast load).
    float4 nsv = *(const float4*)(ns + 4 * (size_t)wave);

    float da = 0.f, n0a = 0.f, n1a = 0.f, db = 0.f, n0b = 0.f, n1b = 0.f;
#pragma unroll
    for (int i = 0; i < 4; ++i) {
        float4 wdv = swd[64 * i + lane];
        float4 w0v = swn0[64 * i + lane];
        float4 w1v = swn1[64 * i + lane];
        da  = fmaf(va[i].x, wdv.x, fmaf(va[i].y, wdv.y, fmaf(va[i].z, wdv.z, fmaf(va[i].w, wdv.w, da))));
        n0a = fmaf(va[i].x, w0v.x, fmaf(va[i].y, w0v.y, fmaf(va[i].z, w0v.z, fmaf(va[i].w, w0v.w, n0a))));
        n1a = fmaf(va[i].x, w1v.x, fmaf(va[i].y, w1v.y, fmaf(va[i].z, w1v.z, fmaf(va[i].w, w1v.w, n1a))));
        db  = fmaf(vb[i].x, wdv.x, fmaf(vb[i].y, wdv.y, fmaf(vb[i].z, wdv.z, fmaf(vb[i].w, wdv.w, db))));
        n0b = fmaf(vb[i].x, w0v.x, fmaf(vb[i].y, w0v.y, fmaf(vb[i].z, w0v.z, fmaf(vb[i].w, w0v.w, n0b))));
        n1b = fmaf(vb[i].x, w1v.x, fmaf(vb[i].y, w1v.y, fmaf(vb[i].z, w1v.z, fmaf(vb[i].w, w1v.w, n1b))));
    }

    // ---- Parity-split reduction: even lanes -> row A sums, odd -> row B. ----
    const bool odd = lane & 1;
    float rd  = odd ? db  : da;   float sd  = odd ? da  : db;
    float rn0 = odd ? n0b : n0a;  float sn0 = odd ? n0a : n0b;
    float rn1 = odd ? n1b : n1a;  float sn1 = odd ? n1a : n1b;
    rd  += __shfl_xor(sd, 1);     // pair-exchange stage
    rn0 += __shfl_xor(sn0, 1);
    rn1 += __shfl_xor(sn1, 1);
#pragma unroll
    for (int o = 2; o <= 32; o <<= 1) {           // parity-preserving stages
        rd  += __shfl_xor(rd, o);
        rn0 += __shfl_xor(rn0, o);
        rn1 += __shfl_xor(rn1, o);
    }
    // rd/rn0/rn1: even lanes hold full row-A sums, odd lanes full row-B sums.

    // ---- Epilogue: lane parity r selects the row; no sum selects needed. ----
    const int r = lane & 1;
    float ns0 = r ? nsv.z : nsv.x;
    float ns1 = r ? nsv.w : nsv.y;

    float std0 = softplusf(rn0) + 0.01f;
    float std1 = softplusf(rn1) + 0.01f;
    float hd = rd + ns1 * std1 - ns0 * std0;      // h1 - h0
    float ad = fabsf(hd);
    float e  = expf(-ad);                          // exp(h_min - h_max)
    float inv = 1.0f / (1.0f + e);
    float pmax = inv;                              // == reference's sorted p0
    float pmin = e * inv;
    float ent  = log1pf(e) + pmin * ad;            // -(l0 ln l0 + l1 ln l1)
    bool first   = (hd <= 0.0f);                   // l0 >= l1 (stable argsort)
    bool toponly = (pmax > 0.7f);                  // cum > TOP_P predicate

    double imp0 = (double)pmax;
    double imp1 = toponly ? 0.0 : (double)pmin;
    double entd = (double)ent;

    // Stores: lanes 0,1 hold rows r0, r0+1.
    if (lane < 2) {
        float w0, w1;
        if (toponly) { w0 = first ? 1.f : 0.f; w1 = 1.f - w0; }
        else         { w0 = 1.f; w1 = 1.f; }
        *(float2*)(out + 4 * (size_t)wave + 2 * r) = make_float2(w0, w1);
        out[OUT_DEC + 2 * (size_t)wave + r] = toponly ? 0.f : 1.f;
    }

    // Wave totals: lanes 0+1 (rows A+B); both hold the wave partial after xor-1.
    imp0 += __shfl_xor(imp0, 1);
    imp1 += __shfl_xor(imp1, 1);
    entd += __shfl_xor(entd, 1);

    // ---- Block partial -> global; last block finishes the scalar loss. ----
    __shared__ double sred[4][3];
    __shared__ int isLast;
    if (lane == 0) {
        sred[wid][0] = imp0; sred[wid][1] = imp1; sred[wid][2] = entd;
    }
    __syncthreads();
    if (t == 0) {
        double a = 0, b = 0, e2 = 0;
#pragma unroll
        for (int w = 0; w < 4; ++w) { a += sred[w][0]; b += sred[w][1]; e2 += sred[w][2]; }
        size_t o = 3 * (size_t)blockIdx.x;
        part[o] = a; part[o + 1] = b; part[o + 2] = e2;
        __threadfence();                            // release: flush part[] to device scope
        unsigned int old = atomicAdd(counter, 1u);  // device-scope by default
        isLast = (old == (unsigned)(BLOCKS - 1));
    }
    __syncthreads();
    if (isLast) {                                   // block-uniform branch
        __threadfence();                            // acquire: invalidate before reading part[]
        double s0 = 0, s1 = 0, s2 = 0;
        for (int i = t; i < BLOCKS; i += 256) {     // 16 iterations, fixed order
            s0 += part[3 * i + 0];
            s1 += part[3 * i + 1];
            s2 += part[3 * i + 2];
        }
#pragma unroll
        for (int o = 32; o; o >>= 1) {
            s0 += __shfl_xor(s0, o);
            s1 += __shfl_xor(s1, o);
            s2 += __shfl_xor(s2, o);
        }
        __shared__ double sl[4][3];
        if (lane == 0) { sl[wid][0] = s0; sl[wid][1] = s1; sl[wid][2] = s2; }
        __syncthreads();
        if (t == 0) {
            double a = 0, b = 0, ent2 = 0;
#pragma unroll
            for (int w = 0; w < 4; ++w) { a += sl[w][0]; b += sl[w][1]; ent2 += sl[w][2]; }
            double mean = 0.5 * (a + b);
            double var  = 0.5 * (a - b) * (a - b);   // ddof=1, E=2
            double li   = var / (mean * mean + 1e-10);
            double ld   = ent2 / (double)ROWS;
            out[OUT_LOSS] = (float)(li + 0.1 * ld);
        }
    }
}

extern "C" void kernel_launch(void* const* d_in, const int* in_sizes, int n_in,
                              void* d_out, int out_size, void* d_ws, size_t ws_size,
                              hipStream_t stream) {
    const float* x       = (const float*)d_in[0];
    const float* gate_w  = (const float*)d_in[1];
    const float* noise_w = (const float*)d_in[2];
    const float* ns      = (const float*)d_in[3];
    float*  out  = (float*)d_out;
    double* part = (double*)d_ws;                              // 96 KiB
    unsigned int* counter = (unsigned int*)((char*)d_ws + PART_BYTES);

    hipMemsetAsync(counter, 0, sizeof(unsigned int), stream);  // graph-capture safe
    router_fused<<<BLOCKS, 256, 0, stream>>>(x, gate_w, noise_w, ns, out, part, counter);
}

// Round 8
// 31.298 us; speedup vs baseline: 5.2242x; 5.2242x over previous
//
#include <hip/hip_runtime.h>
#include <math.h>

// ExpertRouter: B=8, N=4096, D=1024, E=2  -> rows = 32768
// Outputs (concatenated float32):
//   [0 .. 65535]        expert_weights  [rows,2]  (0/1)
//   [65536 .. 98303]    expert_decisions [rows]   (0/1, "both experts kept")
//   [98304]             gating_loss scalar
//
// R8 = R6 (two-kernel, proven 31.0 us) + parity-split butterfly (18 shuffles
// per wave instead of 36; numerically validated in R7).
// R7 lesson: last-block-done finisher (threadfence + single atomic counter)
// costs ~50ns/block serialized across 8 XCDs -> +200us. Never again at 4K blocks.

constexpr int D = 1024;
constexpr int ROWS = 32768;
constexpr int OUT_DEC = ROWS * 2;   // 65536
constexpr int OUT_LOSS = ROWS * 3;  // 98304
constexpr int BLOCKS = 4096;        // 16384 waves x 2 consecutive rows each

static __device__ __forceinline__ float softplusf(float v) {
    // logaddexp(v, 0) = max(v,0) + log1p(exp(-|v|))  (matches jax.nn.softplus)
    return fmaxf(v, 0.0f) + log1pf(expf(-fabsf(v)));
}

__global__ __launch_bounds__(256) void router_main(
    const float* __restrict__ x,        // [ROWS, D]
    const float* __restrict__ gate_w,   // [2, D]
    const float* __restrict__ noise_w,  // [2, D]
    const float* __restrict__ ns,       // [ROWS, 2]
    float* __restrict__ out,            // [ROWS*3 + 1]
    double* __restrict__ part)          // [BLOCKS*3] per-block partials
{
    const int t    = threadIdx.x;
    const int lane = t & 63;
    const int wid  = t >> 6;                      // wave in block (0..3)
    const int wave = blockIdx.x * 4 + wid;        // 0..16383
    const int r0   = wave * 2;                    // 2 consecutive rows per wave

    // ---- Stage folded weights in LDS: wd = g1-g0, wn0, wn1 (3 KiB). ----
    __shared__ float4 swd[256], swn0[256], swn1[256];
    {
        const float4* g4 = (const float4*)gate_w;
        const float4* n4 = (const float4*)noise_w;
        float4 g0 = g4[t], g1 = g4[256 + t];
        swd[t]  = make_float4(g1.x - g0.x, g1.y - g0.y, g1.z - g0.z, g1.w - g0.w);
        swn0[t] = n4[t];
        swn1[t] = n4[256 + t];
    }
    __syncthreads();

    // ---- Issue ALL x loads up-front: 2 rows x 4 float4 (unit-stride). ----
    const float4* xa4 = (const float4*)(x + (size_t)r0 * D);
    const float4* xb4 = xa4 + 256;
    float4 va[4], vb[4];
#pragma unroll
    for (int i = 0; i < 4; ++i) va[i] = xa4[64 * i + lane];
#pragma unroll
    for (int i = 0; i < 4; ++i) vb[i] = xb4[64 * i + lane];

    // Noise samples for rows r0, r0+1 (wave-uniform broadcast load).
    float4 nsv = *(const float4*)(ns + 4 * (size_t)wave);

    float da = 0.f, n0a = 0.f, n1a = 0.f, db = 0.f, n0b = 0.f, n1b = 0.f;
#pragma unroll
    for (int i = 0; i < 4; ++i) {
        float4 wdv = swd[64 * i + lane];
        float4 w0v = swn0[64 * i + lane];
        float4 w1v = swn1[64 * i + lane];
        da  = fmaf(va[i].x, wdv.x, fmaf(va[i].y, wdv.y, fmaf(va[i].z, wdv.z, fmaf(va[i].w, wdv.w, da))));
        n0a = fmaf(va[i].x, w0v.x, fmaf(va[i].y, w0v.y, fmaf(va[i].z, w0v.z, fmaf(va[i].w, w0v.w, n0a))));
        n1a = fmaf(va[i].x, w1v.x, fmaf(va[i].y, w1v.y, fmaf(va[i].z, w1v.z, fmaf(va[i].w, w1v.w, n1a))));
        db  = fmaf(vb[i].x, wdv.x, fmaf(vb[i].y, wdv.y, fmaf(vb[i].z, wdv.z, fmaf(vb[i].w, wdv.w, db))));
        n0b = fmaf(vb[i].x, w0v.x, fmaf(vb[i].y, w0v.y, fmaf(vb[i].z, w0v.z, fmaf(vb[i].w, w0v.w, n0b))));
        n1b = fmaf(vb[i].x, w1v.x, fmaf(vb[i].y, w1v.y, fmaf(vb[i].z, w1v.z, fmaf(vb[i].w, w1v.w, n1b))));
    }

    // ---- Parity-split reduction: even lanes -> row A sums, odd -> row B. ----
    const bool odd = lane & 1;
    float rd  = odd ? db  : da;   float sd  = odd ? da  : db;
    float rn0 = odd ? n0b : n0a;  float sn0 = odd ? n0a : n0b;
    float rn1 = odd ? n1b : n1a;  float sn1 = odd ? n1a : n1b;
    rd  += __shfl_xor(sd, 1);     // pair-exchange stage
    rn0 += __shfl_xor(sn0, 1);
    rn1 += __shfl_xor(sn1, 1);
#pragma unroll
    for (int o = 2; o <= 32; o <<= 1) {           // parity-preserving stages
        rd  += __shfl_xor(rd, o);
        rn0 += __shfl_xor(rn0, o);
        rn1 += __shfl_xor(rn1, o);
    }
    // rd/rn0/rn1: even lanes hold full row-A sums, odd lanes full row-B sums.

    // ---- Epilogue: lane parity r selects the row; no sum selects needed. ----
    const int r = lane & 1;
    float ns0 = r ? nsv.z : nsv.x;
    float ns1 = r ? nsv.w : nsv.y;

    float std0 = softplusf(rn0) + 0.01f;
    float std1 = softplusf(rn1) + 0.01f;
    float hd = rd + ns1 * std1 - ns0 * std0;      // h1 - h0
    float ad = fabsf(hd);
    float e  = expf(-ad);                          // exp(h_min - h_max)
    float inv = 1.0f / (1.0f + e);
    float pmax = inv;                              // == reference's sorted p0
    float pmin = e * inv;
    float ent  = log1pf(e) + pmin * ad;            // -(l0 ln l0 + l1 ln l1)
    bool first   = (hd <= 0.0f);                   // l0 >= l1 (stable argsort)
    bool toponly = (pmax > 0.7f);                  // cum > TOP_P predicate

    double imp0 = (double)pmax;
    double imp1 = toponly ? 0.0 : (double)pmin;
    double entd = (double)ent;

    // Stores: lanes 0,1 hold rows r0, r0+1.
    if (lane < 2) {
        float w0, w1;
        if (toponly) { w0 = first ? 1.f : 0.f; w1 = 1.f - w0; }
        else         { w0 = 1.f; w1 = 1.f; }
        *(float2*)(out + 4 * (size_t)wave + 2 * r) = make_float2(w0, w1);
        out[OUT_DEC + 2 * (size_t)wave + r] = toponly ? 0.f : 1.f;
    }

    // Wave totals: lanes 0+1 (rows A+B); both hold the wave partial after xor-1.
    imp0 += __shfl_xor(imp0, 1);
    imp1 += __shfl_xor(imp1, 1);
    entd += __shfl_xor(entd, 1);

    // Block-level reduction of per-wave partials; ONE plain store per block.
    __shared__ double sred[4][3];
    if (lane == 0) {
        sred[wid][0] = imp0; sred[wid][1] = imp1; sred[wid][2] = entd;
    }
    __syncthreads();
    if (t == 0) {
        double a = 0, b = 0, e2 = 0;
#pragma unroll
        for (int w = 0; w < 4; ++w) { a += sred[w][0]; b += sred[w][1]; e2 += sred[w][2]; }
        part[3 * (size_t)blockIdx.x + 0] = a;
        part[3 * (size_t)blockIdx.x + 1] = b;
        part[3 * (size_t)blockIdx.x + 2] = e2;
    }
}

__global__ __launch_bounds__(1024) void router_final(const double* __restrict__ part,
                                                     float* __restrict__ out) {
    const int t    = threadIdx.x;
    const int lane = t & 63;
    const int wid  = t >> 6;                      // 16 waves
    double s0 = 0, s1 = 0, s2 = 0;
#pragma unroll
    for (int i = t; i < BLOCKS; i += 1024) {      // 4 iterations
        s0 += part[3 * i + 0];
        s1 += part[3 * i + 1];
        s2 += part[3 * i + 2];
    }
#pragma unroll
    for (int o = 32; o; o >>= 1) {
        s0 += __shfl_xor(s0, o);
        s1 += __shfl_xor(s1, o);
        s2 += __shfl_xor(s2, o);
    }
    __shared__ double sl[16][3];
    if (lane == 0) { sl[wid][0] = s0; sl[wid][1] = s1; sl[wid][2] = s2; }
    __syncthreads();
    if (t == 0) {
        double a = 0, b = 0, ent = 0;
#pragma unroll
        for (int w = 0; w < 16; ++w) { a += sl[w][0]; b += sl[w][1]; ent += sl[w][2]; }
        double mean = 0.5 * (a + b);
        double var  = 0.5 * (a - b) * (a - b);   // ddof=1, E=2
        double li   = var / (mean * mean + 1e-10);
        double ld   = ent / (double)ROWS;
        out[OUT_LOSS] = (float)(li + 0.1 * ld);
    }
}

extern "C" void kernel_launch(void* const* d_in, const int* in_sizes, int n_in,
                              void* d_out, int out_size, void* d_ws, size_t ws_size,
                              hipStream_t stream) {
    const float* x       = (const float*)d_in[0];
    const float* gate_w  = (const float*)d_in[1];
    const float* noise_w = (const float*)d_in[2];
    const float* ns      = (const float*)d_in[3];
    float*  out  = (float*)d_out;
    double* part = (double*)d_ws;   // BLOCKS*3 doubles = 96 KiB

    router_main<<<BLOCKS, 256, 0, stream>>>(x, gate_w, noise_w, ns, out, part);
    router_final<<<1, 1024, 0, stream>>>(part, out);
}

// Round 9
// 30.469 us; speedup vs baseline: 5.3663x; 1.0272x over previous
//
#include <hip/hip_runtime.h>
#include <math.h>

// ExpertRouter: B=8, N=4096, D=1024, E=2  -> rows = 32768
// Outputs (concatenated float32):
//   [0 .. 65535]        expert_weights  [rows,2]  (0/1)
//   [65536 .. 98303]    expert_decisions [rows]   (0/1, "both experts kept")
//   [98304]             gating_loss scalar
//
// R9 vs R8: 4 rows/wave (8192 waves) to amortize per-wave fixed costs
// (LDS weight reads, butterfly, transcendental epilogue) across 2x rows.
// All 16 x-float4 loads issued before the weight-staging prologue.
// R7 lesson stands: no single-counter last-block finisher at 4K blocks.

constexpr int D = 1024;
constexpr int ROWS = 32768;
constexpr int OUT_DEC = ROWS * 2;   // 65536
constexpr int OUT_LOSS = ROWS * 3;  // 98304
constexpr int BLOCKS = 2048;        // 8192 waves x 4 consecutive rows each

static __device__ __forceinline__ float softplusf(float v) {
    // logaddexp(v, 0) = max(v,0) + log1p(exp(-|v|))  (matches jax.nn.softplus)
    return fmaxf(v, 0.0f) + log1pf(expf(-fabsf(v)));
}

__global__ __launch_bounds__(256) void router_main(
    const float* __restrict__ x,        // [ROWS, D]
    const float* __restrict__ gate_w,   // [2, D]
    const float* __restrict__ noise_w,  // [2, D]
    const float* __restrict__ ns,       // [ROWS, 2]
    float* __restrict__ out,            // [ROWS*3 + 1]
    double* __restrict__ part)          // [BLOCKS*3] per-block partials
{
    const int t    = threadIdx.x;
    const int lane = t & 63;
    const int wid  = t >> 6;                      // wave in block (0..3)
    const int wave = blockIdx.x * 4 + wid;        // 0..8191
    const int r0   = wave * 4;                    // 4 consecutive rows per wave

    // ---- Issue ALL x loads first: 4 rows x 4 float4 (unit-stride). ----
    const float4* xr4 = (const float4*)(x + (size_t)r0 * D);
    float4 vA[4], vB[4], vC[4], vD[4];
#pragma unroll
    for (int i = 0; i < 4; ++i) vA[i] = xr4[        64 * i + lane];
#pragma unroll
    for (int i = 0; i < 4; ++i) vB[i] = xr4[256  + 64 * i + lane];
#pragma unroll
    for (int i = 0; i < 4; ++i) vC[i] = xr4[512  + 64 * i + lane];
#pragma unroll
    for (int i = 0; i < 4; ++i) vD[i] = xr4[768  + 64 * i + lane];

    // Noise samples for rows r0..r0+3 (wave-uniform broadcast loads).
    float4 nsA = *(const float4*)(ns + 8 * (size_t)wave);      // rows 0,1
    float4 nsB = *(const float4*)(ns + 8 * (size_t)wave + 4);  // rows 2,3

    // ---- Stage folded weights in LDS: wd = g1-g0, wn0, wn1 (12 KiB). ----
    __shared__ float4 swd[256], swn0[256], swn1[256];
    {
        const float4* g4 = (const float4*)gate_w;
        const float4* n4 = (const float4*)noise_w;
        float4 g0 = g4[t], g1 = g4[256 + t];
        swd[t]  = make_float4(g1.x - g0.x, g1.y - g0.y, g1.z - g0.z, g1.w - g0.w);
        swn0[t] = n4[t];
        swn1[t] = n4[256 + t];
    }
    __syncthreads();

    float dA = 0.f, nA0 = 0.f, nA1 = 0.f, dB = 0.f, nB0 = 0.f, nB1 = 0.f;
    float dC = 0.f, nC0 = 0.f, nC1 = 0.f, dD = 0.f, nD0 = 0.f, nD1 = 0.f;
#pragma unroll
    for (int i = 0; i < 4; ++i) {
        float4 wdv = swd[64 * i + lane];
        float4 w0v = swn0[64 * i + lane];
        float4 w1v = swn1[64 * i + lane];
        dA  = fmaf(vA[i].x, wdv.x, fmaf(vA[i].y, wdv.y, fmaf(vA[i].z, wdv.z, fmaf(vA[i].w, wdv.w, dA))));
        nA0 = fmaf(vA[i].x, w0v.x, fmaf(vA[i].y, w0v.y, fmaf(vA[i].z, w0v.z, fmaf(vA[i].w, w0v.w, nA0))));
        nA1 = fmaf(vA[i].x, w1v.x, fmaf(vA[i].y, w1v.y, fmaf(vA[i].z, w1v.z, fmaf(vA[i].w, w1v.w, nA1))));
        dB  = fmaf(vB[i].x, wdv.x, fmaf(vB[i].y, wdv.y, fmaf(vB[i].z, wdv.z, fmaf(vB[i].w, wdv.w, dB))));
        nB0 = fmaf(vB[i].x, w0v.x, fmaf(vB[i].y, w0v.y, fmaf(vB[i].z, w0v.z, fmaf(vB[i].w, w0v.w, nB0))));
        nB1 = fmaf(vB[i].x, w1v.x, fmaf(vB[i].y, w1v.y, fmaf(vB[i].z, w1v.z, fmaf(vB[i].w, w1v.w, nB1))));
        dC  = fmaf(vC[i].x, wdv.x, fmaf(vC[i].y, wdv.y, fmaf(vC[i].z, wdv.z, fmaf(vC[i].w, wdv.w, dC))));
        nC0 = fmaf(vC[i].x, w0v.x, fmaf(vC[i].y, w0v.y, fmaf(vC[i].z, w0v.z, fmaf(vC[i].w, w0v.w, nC0))));
        nC1 = fmaf(vC[i].x, w1v.x, fmaf(vC[i].y, w1v.y, fmaf(vC[i].z, w1v.z, fmaf(vC[i].w, w1v.w, nC1))));
        dD  = fmaf(vD[i].x, wdv.x, fmaf(vD[i].y, wdv.y, fmaf(vD[i].z, wdv.z, fmaf(vD[i].w, wdv.w, dD))));
        nD0 = fmaf(vD[i].x, w0v.x, fmaf(vD[i].y, w0v.y, fmaf(vD[i].z, w0v.z, fmaf(vD[i].w, w0v.w, nD0))));
        nD1 = fmaf(vD[i].x, w1v.x, fmaf(vD[i].y, w1v.y, fmaf(vD[i].z, w1v.z, fmaf(vD[i].w, w1v.w, nD1))));
    }

    // ---- 4-way parity-split reduction: lane (l&3) ends with row (l&3). ----
    // Stage 1 (xor 1): merge row pairs {A,B} and {C,D}.
    const bool p1 = lane & 1;
    float kAB_d  = p1 ? dB  : dA,  sAB_d  = p1 ? dA  : dB;
    float kAB_n0 = p1 ? nB0 : nA0, sAB_n0 = p1 ? nA0 : nB0;
    float kAB_n1 = p1 ? nB1 : nA1, sAB_n1 = p1 ? nA1 : nB1;
    float kCD_d  = p1 ? dD  : dC,  sCD_d  = p1 ? dC  : dD;
    float kCD_n0 = p1 ? nD0 : nC0, sCD_n0 = p1 ? nC0 : nD0;
    float kCD_n1 = p1 ? nD1 : nC1, sCD_n1 = p1 ? nC1 : nD1;
    kAB_d  += __shfl_xor(sAB_d, 1);
    kAB_n0 += __shfl_xor(sAB_n0, 1);
    kAB_n1 += __shfl_xor(sAB_n1, 1);
    kCD_d  += __shfl_xor(sCD_d, 1);
    kCD_n0 += __shfl_xor(sCD_n0, 1);
    kCD_n1 += __shfl_xor(sCD_n1, 1);
    // Stage 2 (xor 2): select AB vs CD.
    const bool p2 = lane & 2;
    float rd  = p2 ? kCD_d  : kAB_d,  s2_d  = p2 ? kAB_d  : kCD_d;
    float rn0 = p2 ? kCD_n0 : kAB_n0, s2_n0 = p2 ? kAB_n0 : kCD_n0;
    float rn1 = p2 ? kCD_n1 : kAB_n1, s2_n1 = p2 ? kAB_n1 : kCD_n1;
    rd  += __shfl_xor(s2_d, 2);
    rn0 += __shfl_xor(s2_n0, 2);
    rn1 += __shfl_xor(s2_n1, 2);
    // Stages 4..32: parity-preserving.
#pragma unroll
    for (int o = 4; o <= 32; o <<= 1) {
        rd  += __shfl_xor(rd, o);
        rn0 += __shfl_xor(rn0, o);
        rn1 += __shfl_xor(rn1, o);
    }
    // rd/rn0/rn1: lane l holds full sums of row (l&3).

    // ---- Epilogue: lane group-index r = lane&3 handles row r0+r. ----
    const int r = lane & 3;
    float ns0 = (r == 0) ? nsA.x : (r == 1) ? nsA.z : (r == 2) ? nsB.x : nsB.z;
    float ns1 = (r == 0) ? nsA.y : (r == 1) ? nsA.w : (r == 2) ? nsB.y : nsB.w;

    float std0 = softplusf(rn0) + 0.01f;
    float std1 = softplusf(rn1) + 0.01f;
    float hd = rd + ns1 * std1 - ns0 * std0;      // h1 - h0
    float ad = fabsf(hd);
    float e  = expf(-ad);                          // exp(h_min - h_max)
    float inv = 1.0f / (1.0f + e);
    float pmax = inv;                              // == reference's sorted p0
    float pmin = e * inv;
    float ent  = log1pf(e) + pmin * ad;            // -(l0 ln l0 + l1 ln l1)
    bool first   = (hd <= 0.0f);                   // l0 >= l1 (stable argsort)
    bool toponly = (pmax > 0.7f);                  // cum > TOP_P predicate

    double imp0 = (double)pmax;
    double imp1 = toponly ? 0.0 : (double)pmin;
    double entd = (double)ent;

    // Stores: lanes 0..3 hold rows r0..r0+3.
    if (lane < 4) {
        float w0, w1;
        if (toponly) { w0 = first ? 1.f : 0.f; w1 = 1.f - w0; }
        else         { w0 = 1.f; w1 = 1.f; }
        *(float2*)(out + 8 * (size_t)wave + 2 * r) = make_float2(w0, w1);
        out[OUT_DEC + 4 * (size_t)wave + r] = toponly ? 0.f : 1.f;
    }

    // Wave totals over the 4-lane group (xor 1, xor 2); lane 0 holds them.
    imp0 += __shfl_xor(imp0, 1);  imp0 += __shfl_xor(imp0, 2);
    imp1 += __shfl_xor(imp1, 1);  imp1 += __shfl_xor(imp1, 2);
    entd += __shfl_xor(entd, 1);  entd += __shfl_xor(entd, 2);

    // Block-level reduction of per-wave partials; ONE plain store per block.
    __shared__ double sred[4][3];
    if (lane == 0) {
        sred[wid][0] = imp0; sred[wid][1] = imp1; sred[wid][2] = entd;
    }
    __syncthreads();
    if (t == 0) {
        double a = 0, b = 0, e2 = 0;
#pragma unroll
        for (int w = 0; w < 4; ++w) { a += sred[w][0]; b += sred[w][1]; e2 += sred[w][2]; }
        part[3 * (size_t)blockIdx.x + 0] = a;
        part[3 * (size_t)blockIdx.x + 1] = b;
        part[3 * (size_t)blockIdx.x + 2] = e2;
    }
}

__global__ __launch_bounds__(1024) void router_final(const double* __restrict__ part,
                                                     float* __restrict__ out) {
    const int t    = threadIdx.x;
    const int lane = t & 63;
    const int wid  = t >> 6;                      // 16 waves
    double s0 = 0, s1 = 0, s2 = 0;
#pragma unroll
    for (int i = t; i < BLOCKS; i += 1024) {      // 2 iterations
        s0 += part[3 * i + 0];
        s1 += part[3 * i + 1];
        s2 += part[3 * i + 2];
    }
#pragma unroll
    for (int o = 32; o; o >>= 1) {
        s0 += __shfl_xor(s0, o);
        s1 += __shfl_xor(s1, o);
        s2 += __shfl_xor(s2, o);
    }
    __shared__ double sl[16][3];
    if (lane == 0) { sl[wid][0] = s0; sl[wid][1] = s1; sl[wid][2] = s2; }
    __syncthreads();
    if (t == 0) {
        double a = 0, b = 0, ent = 0;
#pragma unroll
        for (int w = 0; w < 16; ++w) { a += sl[w][0]; b += sl[w][1]; ent += sl[w][2]; }
        double mean = 0.5 * (a + b);
        double var  = 0.5 * (a - b) * (a - b);   // ddof=1, E=2
        double li   = var / (mean * mean + 1e-10);
        double ld   = ent / (double)ROWS;
        out[OUT_LOSS] = (float)(li + 0.1 * ld);
    }
}

extern "C" void kernel_launch(void* const* d_in, const int* in_sizes, int n_in,
                              void* d_out, int out_size, void* d_ws, size_t ws_size,
                              hipStream_t stream) {
    const float* x       = (const float*)d_in[0];
    const float* gate_w  = (const float*)d_in[1];
    const float* noise_w = (const float*)d_in[2];
    const float* ns      = (const float*)d_in[3];
    float*  out  = (float*)d_out;
    double* part = (double*)d_ws;   // BLOCKS*3 doubles = 48 KiB

    router_main<<<BLOCKS, 256, 0, stream>>>(x, gate_w, noise_w, ns, out, part);
    router_final<<<1, 1024, 0, stream>>>(part, out);
}

// Round 10
// 30.050 us; speedup vs baseline: 5.4412x; 1.0139x over previous
//
#include <hip/hip_runtime.h>
#include <math.h>

// ExpertRouter: B=8, N=4096, D=1024, E=2  -> rows = 32768
// Outputs (concatenated float32):
//   [0 .. 65535]        expert_weights  [rows,2]  (0/1)
//   [65536 .. 98303]    expert_decisions [rows]   (0/1, "both experts kept")
//   [98304]             gating_loss scalar
//
// R10 = R9 + NONTEMPORAL x loads (nt flag: no L2/L3 retention). Probe theory:
// steady-state FETCH_SIZE=66MB shows half of x is served from L3 at a mixed
// effective 5.2 TB/s across three structurally-different kernels; if the
// L3-hit path is the drag, forcing pure HBM streaming should reach ~6.3 TB/s.
// Null result => declared read-path ceiling, roofline.

constexpr int D = 1024;
constexpr int ROWS = 32768;
constexpr int OUT_DEC = ROWS * 2;   // 65536
constexpr int OUT_LOSS = ROWS * 3;  // 98304
constexpr int BLOCKS = 2048;        // 8192 waves x 4 consecutive rows each

typedef float f4_t __attribute__((ext_vector_type(4)));  // raw vec4 for nt loads

static __device__ __forceinline__ float softplusf(float v) {
    // logaddexp(v, 0) = max(v,0) + log1p(exp(-|v|))  (matches jax.nn.softplus)
    return fmaxf(v, 0.0f) + log1pf(expf(-fabsf(v)));
}

__global__ __launch_bounds__(256) void router_main(
    const float* __restrict__ x,        // [ROWS, D]
    const float* __restrict__ gate_w,   // [2, D]
    const float* __restrict__ noise_w,  // [2, D]
    const float* __restrict__ ns,       // [ROWS, 2]
    float* __restrict__ out,            // [ROWS*3 + 1]
    double* __restrict__ part)          // [BLOCKS*3] per-block partials
{
    const int t    = threadIdx.x;
    const int lane = t & 63;
    const int wid  = t >> 6;                      // wave in block (0..3)
    const int wave = blockIdx.x * 4 + wid;        // 0..8191
    const int r0   = wave * 4;                    // 4 consecutive rows per wave

    // ---- Issue ALL x loads first: 4 rows x 4 float4, NONTEMPORAL. ----
    const f4_t* xr4 = (const f4_t*)(x + (size_t)r0 * D);
    f4_t vA[4], vB[4], vC[4], vD[4];
#pragma unroll
    for (int i = 0; i < 4; ++i) vA[i] = __builtin_nontemporal_load(&xr4[       64 * i + lane]);
#pragma unroll
    for (int i = 0; i < 4; ++i) vB[i] = __builtin_nontemporal_load(&xr4[256  + 64 * i + lane]);
#pragma unroll
    for (int i = 0; i < 4; ++i) vC[i] = __builtin_nontemporal_load(&xr4[512  + 64 * i + lane]);
#pragma unroll
    for (int i = 0; i < 4; ++i) vD[i] = __builtin_nontemporal_load(&xr4[768  + 64 * i + lane]);

    // Noise samples for rows r0..r0+3 (wave-uniform broadcast loads, cached).
    float4 nsA = *(const float4*)(ns + 8 * (size_t)wave);      // rows 0,1
    float4 nsB = *(const float4*)(ns + 8 * (size_t)wave + 4);  // rows 2,3

    // ---- Stage folded weights in LDS: wd = g1-g0, wn0, wn1. ----
    __shared__ float4 swd[256], swn0[256], swn1[256];
    {
        const float4* g4 = (const float4*)gate_w;
        const float4* n4 = (const float4*)noise_w;
        float4 g0 = g4[t], g1 = g4[256 + t];
        swd[t]  = make_float4(g1.x - g0.x, g1.y - g0.y, g1.z - g0.z, g1.w - g0.w);
        swn0[t] = n4[t];
        swn1[t] = n4[256 + t];
    }
    __syncthreads();

    float dA = 0.f, nA0 = 0.f, nA1 = 0.f, dB = 0.f, nB0 = 0.f, nB1 = 0.f;
    float dC = 0.f, nC0 = 0.f, nC1 = 0.f, dD = 0.f, nD0 = 0.f, nD1 = 0.f;
#pragma unroll
    for (int i = 0; i < 4; ++i) {
        float4 wdv = swd[64 * i + lane];
        float4 w0v = swn0[64 * i + lane];
        float4 w1v = swn1[64 * i + lane];
        dA  = fmaf(vA[i][0], wdv.x, fmaf(vA[i][1], wdv.y, fmaf(vA[i][2], wdv.z, fmaf(vA[i][3], wdv.w, dA))));
        nA0 = fmaf(vA[i][0], w0v.x, fmaf(vA[i][1], w0v.y, fmaf(vA[i][2], w0v.z, fmaf(vA[i][3], w0v.w, nA0))));
        nA1 = fmaf(vA[i][0], w1v.x, fmaf(vA[i][1], w1v.y, fmaf(vA[i][2], w1v.z, fmaf(vA[i][3], w1v.w, nA1))));
        dB  = fmaf(vB[i][0], wdv.x, fmaf(vB[i][1], wdv.y, fmaf(vB[i][2], wdv.z, fmaf(vB[i][3], wdv.w, dB))));
        nB0 = fmaf(vB[i][0], w0v.x, fmaf(vB[i][1], w0v.y, fmaf(vB[i][2], w0v.z, fmaf(vB[i][3], w0v.w, nB0))));
        nB1 = fmaf(vB[i][0], w1v.x, fmaf(vB[i][1], w1v.y, fmaf(vB[i][2], w1v.z, fmaf(vB[i][3], w1v.w, nB1))));
        dC  = fmaf(vC[i][0], wdv.x, fmaf(vC[i][1], wdv.y, fmaf(vC[i][2], wdv.z, fmaf(vC[i][3], wdv.w, dC))));
        nC0 = fmaf(vC[i][0], w0v.x, fmaf(vC[i][1], w0v.y, fmaf(vC[i][2], w0v.z, fmaf(vC[i][3], w0v.w, nC0))));
        nC1 = fmaf(vC[i][0], w1v.x, fmaf(vC[i][1], w1v.y, fmaf(vC[i][2], w1v.z, fmaf(vC[i][3], w1v.w, nC1))));
        dD  = fmaf(vD[i][0], wdv.x, fmaf(vD[i][1], wdv.y, fmaf(vD[i][2], wdv.z, fmaf(vD[i][3], wdv.w, dD))));
        nD0 = fmaf(vD[i][0], w0v.x, fmaf(vD[i][1], w0v.y, fmaf(vD[i][2], w0v.z, fmaf(vD[i][3], w0v.w, nD0))));
        nD1 = fmaf(vD[i][0], w1v.x, fmaf(vD[i][1], w1v.y, fmaf(vD[i][2], w1v.z, fmaf(vD[i][3], w1v.w, nD1))));
    }

    // ---- 4-way parity-split reduction: lane (l&3) ends with row (l&3). ----
    const bool p1 = lane & 1;
    float kAB_d  = p1 ? dB  : dA,  sAB_d  = p1 ? dA  : dB;
    float kAB_n0 = p1 ? nB0 : nA0, sAB_n0 = p1 ? nA0 : nB0;
    float kAB_n1 = p1 ? nB1 : nA1, sAB_n1 = p1 ? nA1 : nB1;
    float kCD_d  = p1 ? dD  : dC,  sCD_d  = p1 ? dC  : dD;
    float kCD_n0 = p1 ? nD0 : nC0, sCD_n0 = p1 ? nC0 : nD0;
    float kCD_n1 = p1 ? nD1 : nC1, sCD_n1 = p1 ? nC1 : nD1;
    kAB_d  += __shfl_xor(sAB_d, 1);
    kAB_n0 += __shfl_xor(sAB_n0, 1);
    kAB_n1 += __shfl_xor(sAB_n1, 1);
    kCD_d  += __shfl_xor(sCD_d, 1);
    kCD_n0 += __shfl_xor(sCD_n0, 1);
    kCD_n1 += __shfl_xor(sCD_n1, 1);
    const bool p2 = lane & 2;
    float rd  = p2 ? kCD_d  : kAB_d,  s2_d  = p2 ? kAB_d  : kCD_d;
    float rn0 = p2 ? kCD_n0 : kAB_n0, s2_n0 = p2 ? kAB_n0 : kCD_n0;
    float rn1 = p2 ? kCD_n1 : kAB_n1, s2_n1 = p2 ? kAB_n1 : kCD_n1;
    rd  += __shfl_xor(s2_d, 2);
    rn0 += __shfl_xor(s2_n0, 2);
    rn1 += __shfl_xor(s2_n1, 2);
#pragma unroll
    for (int o = 4; o <= 32; o <<= 1) {
        rd  += __shfl_xor(rd, o);
        rn0 += __shfl_xor(rn0, o);
        rn1 += __shfl_xor(rn1, o);
    }
    // rd/rn0/rn1: lane l holds full sums of row (l&3).

    // ---- Epilogue: lane group-index r = lane&3 handles row r0+r. ----
    const int r = lane & 3;
    float ns0 = (r == 0) ? nsA.x : (r == 1) ? nsA.z : (r == 2) ? nsB.x : nsB.z;
    float ns1 = (r == 0) ? nsA.y : (r == 1) ? nsA.w : (r == 2) ? nsB.y : nsB.w;

    float std0 = softplusf(rn0) + 0.01f;
    float std1 = softplusf(rn1) + 0.01f;
    float hd = rd + ns1 * std1 - ns0 * std0;      // h1 - h0
    float ad = fabsf(hd);
    float e  = expf(-ad);                          // exp(h_min - h_max)
    float inv = 1.0f / (1.0f + e);
    float pmax = inv;                              // == reference's sorted p0
    float pmin = e * inv;
    float ent  = log1pf(e) + pmin * ad;            // -(l0 ln l0 + l1 ln l1)
    bool first   = (hd <= 0.0f);                   // l0 >= l1 (stable argsort)
    bool toponly = (pmax > 0.7f);                  // cum > TOP_P predicate

    double imp0 = (double)pmax;
    double imp1 = toponly ? 0.0 : (double)pmin;
    double entd = (double)ent;

    // Stores: lanes 0..3 hold rows r0..r0+3.
    if (lane < 4) {
        float w0, w1;
        if (toponly) { w0 = first ? 1.f : 0.f; w1 = 1.f - w0; }
        else         { w0 = 1.f; w1 = 1.f; }
        *(float2*)(out + 8 * (size_t)wave + 2 * r) = make_float2(w0, w1);
        out[OUT_DEC + 4 * (size_t)wave + r] = toponly ? 0.f : 1.f;
    }

    // Wave totals over the 4-lane group (xor 1, xor 2); lane 0 holds them.
    imp0 += __shfl_xor(imp0, 1);  imp0 += __shfl_xor(imp0, 2);
    imp1 += __shfl_xor(imp1, 1);  imp1 += __shfl_xor(imp1, 2);
    entd += __shfl_xor(entd, 1);  entd += __shfl_xor(entd, 2);

    // Block-level reduction of per-wave partials; ONE plain store per block.
    __shared__ double sred[4][3];
    if (lane == 0) {
        sred[wid][0] = imp0; sred[wid][1] = imp1; sred[wid][2] = entd;
    }
    __syncthreads();
    if (t == 0) {
        double a = 0, b = 0, e2 = 0;
#pragma unroll
        for (int w = 0; w < 4; ++w) { a += sred[w][0]; b += sred[w][1]; e2 += sred[w][2]; }
        part[3 * (size_t)blockIdx.x + 0] = a;
        part[3 * (size_t)blockIdx.x + 1] = b;
        part[3 * (size_t)blockIdx.x + 2] = e2;
    }
}

__global__ __launch_bounds__(1024) void router_final(const double* __restrict__ part,
                                                     float* __restrict__ out) {
    const int t    = threadIdx.x;
    const int lane = t & 63;
    const int wid  = t >> 6;                      // 16 waves
    double s0 = 0, s1 = 0, s2 = 0;
#pragma unroll
    for (int i = t; i < BLOCKS; i += 1024) {      // 2 iterations
        s0 += part[3 * i + 0];
        s1 += part[3 * i + 1];
        s2 += part[3 * i + 2];
    }
#pragma unroll
    for (int o = 32; o; o >>= 1) {
        s0 += __shfl_xor(s0, o);
        s1 += __shfl_xor(s1, o);
        s2 += __shfl_xor(s2, o);
    }
    __shared__ double sl[16][3];
    if (lane == 0) { sl[wid][0] = s0; sl[wid][1] = s1; sl[wid][2] = s2; }
    __syncthreads();
    if (t == 0) {
        double a = 0, b = 0, ent = 0;
#pragma unroll
        for (int w = 0; w < 16; ++w) { a += sl[w][0]; b += sl[w][1]; ent += sl[w][2]; }
        double mean = 0.5 * (a + b);
        double var  = 0.5 * (a - b) * (a - b);   // ddof=1, E=2
        double li   = var / (mean * mean + 1e-10);
        double ld   = ent / (double)ROWS;
        out[OUT_LOSS] = (float)(li + 0.1 * ld);
    }
}

extern "C" void kernel_launch(void* const* d_in, const int* in_sizes, int n_in,
                              void* d_out, int out_size, void* d_ws, size_t ws_size,
                              hipStream_t stream) {
    const float* x       = (const float*)d_in[0];
    const float* gate_w  = (const float*)d_in[1];
    const float* noise_w = (const float*)d_in[2];
    const float* ns      = (const float*)d_in[3];
    float*  out  = (float*)d_out;
    double* part = (double*)d_ws;   // BLOCKS*3 doubles = 48 KiB

    router_main<<<BLOCKS, 256, 0, stream>>>(x, gate_w, noise_w, ns, out, part);
    router_final<<<1, 1024, 0, stream>>>(part, out);
}